// Round 6
// baseline (3630.394 us; speedup 1.0000x reference)
//
#include <hip/hip_runtime.h>
#include <hip/hip_bf16.h>

// Problem sizes (fixed)
#define BB 32
#define TT 512
#define HH 1024
#define II 1024
#define G4H 4096
#define BH  (BB * HH)          // 32768
#define HD  8                  // h-buffer depth (slots); buffer_inv every HD phases
#define HMASK (HD - 1)
#define NPH (TT + 2)           // 514 phases: L0 @ u (u<=511), L1 @ u-2 (u>=2)

typedef __bf16 bf16x8_t __attribute__((ext_vector_type(8)));
typedef float f32x4_t __attribute__((ext_vector_type(4)));
typedef int i32x4_t __attribute__((ext_vector_type(4)));
typedef unsigned long long u64;

// async global(16B/lane) -> LDS(base + lane*16)
__device__ __forceinline__ void gload16(const void* g, void* l) {
    __builtin_amdgcn_global_load_lds(
        (const __attribute__((address_space(1))) unsigned int*)g,
        (__attribute__((address_space(3))) unsigned int*)l, 16, 0, 0);
}

// ---------------------------------------------------------------------------
// Zero h0 slot 0, h1 slot 7 (the two slots read before first write), and all
// flag/replica lines, via agent-scope stores (durable at coherence point).
// grid 256x256 = 65536 threads.
// ---------------------------------------------------------------------------
__global__ void init_bufs(unsigned* __restrict__ h0w, unsigned* __restrict__ h1w,
                          unsigned* __restrict__ cnt) {
    int i = blockIdx.x * 256 + threadIdx.x;
    if (i < 16384)
        __hip_atomic_store(h0w + i, 0u, __ATOMIC_RELAXED, __HIP_MEMORY_SCOPE_AGENT);
    else if (i < 32768)
        __hip_atomic_store(h1w + 7 * 16384 + (i - 16384), 0u,
                           __ATOMIC_RELAXED, __HIP_MEMORY_SCOPE_AGENT);
    else if (i < 49152)
        __hip_atomic_store(cnt + (i - 32768), 0u, __ATOMIC_RELAXED, __HIP_MEMORY_SCOPE_AGENT);
    else
        __hip_atomic_store(cnt + 16384 + (i - 49152), 0u,
                           __ATOMIC_RELAXED, __HIP_MEMORY_SCOPE_AGENT);
}

// ---------------------------------------------------------------------------
// Weight shuffle: fp32 [4096][1024] -> bf16 B-fragment order. (unchanged)
// ---------------------------------------------------------------------------
__global__ void shuffle_w(const float* __restrict__ src, __hip_bfloat16* __restrict__ dst) {
    size_t i = (size_t)blockIdx.x * 256 + threadIdx.x;   // 0 .. 4M-1
    int jj   = (int)(i & 7);
    int lane = (int)((i >> 3) & 63);
    int kb   = (int)((i >> 9) & 15);
    int kh   = (int)((i >> 13) & 1);
    int tau  = (int)((i >> 14) & 1);
    int hg   = (int)(i >> 15);
    int n = lane & 15, q = lane >> 4;
    int row = (2 * tau + (n >> 3)) * 1024 + hg * 8 + (n & 7);
    int col = kh * 512 + kb * 32 + q * 8 + jj;
    dst[i] = __float2bfloat16(src[(size_t)row * II + col]);
}

// ---------------------------------------------------------------------------
// x [B][T][I] fp32 -> xb [T][B][I] bf16 (unchanged)
// ---------------------------------------------------------------------------
__global__ void convert_x(const float* __restrict__ x, __hip_bfloat16* __restrict__ xb) {
    size_t i = (size_t)blockIdx.x * 256 + threadIdx.x;   // T*B*I
    int ii = (int)(i & 1023);
    int b  = (int)((i >> 10) & 31);
    int t  = (int)(i >> 15);
    xb[i] = __float2bfloat16(x[((size_t)b * TT + t) * II + ii]);
}

// ---------------------------------------------------------------------------
// Persistent fused 2-layer LSTM — SPLIT-PHASE DUAL-BARRIER PIPELINE.
// 256 WGs (1/CU) x 512 threads (8 waves).
//
// Theory (r5 post-mortem): phase floor = serial chain {release -> h-DMA ->
// GEMM -> pointwise -> store ack -> flag -> detect -> release} with both
// layers lockstepped behind ONE barrier. The h0 and h1 recurrences are
// independent serial chains (cross-link h0->L1 has >=1 phase slack), so give
// each its own barrier (A for h0, B for h1) and run the sections back-to-back:
// each barrier's detect/release hops are assembled while WGs execute the
// OPPOSITE section -> barrier RT hides under compute.
//   phase u: [relA(u) | h0_{u-1} DMA ∥ x-GEMM | L0 GEMM | P0 | h0_u store+ack
//             | flagA=u+1 | x-DMA(u+1)]  then
//            [relB(u) | h1_{u-3} DMA ∥ L1-h0-side GEMM | L1 GEMM | P1 |
//             h1_{u-2} store+ack | flagB=u+1 | out_{u-2}]
// relA(u): all flagA==u (posted u-1 S0) -> certifies h0_{u-1}; also all
// flagB>=u-1 holds transitively for h1_{u-3} via relB(u-1) observed last
// phase. relB(u): all flagB==u (posted u-1 S1) -> certifies h1_{u-3}.
// L1 lags 2 phases: consumes h0_{u-2} (LDS double-buffer) + h1_{u-3}.
// All 8 waves do ONE layer's GEMM at a time (psum[8] K-slices). Each wave
// self-DMAs exactly the 8KB it reads (issue -> own vmcnt(0) -> sched_barrier
// -> ds_read; guide rule #18) -> no all-wave barrier on the DMA.
// Kept from r2-r5 (all verified): depth-8 h slots + ONE buffer_inv per 8
// phases; 16B write-through h stores + wave-local vmcnt drain before flag;
// tree barrier (master hg==bh polls 128 flags 1/thread, 16 release replicas);
// out stores off the ack path; bounded spins as hang safety.
// LDS: 96KB astage(x 32K + h0 dbuf 64K... = x32K+h0 64K+h1 32K) + 22KB = 153KB.
// ---------------------------------------------------------------------------
__global__ __launch_bounds__(512, 2)
void lstm_persist(const __hip_bfloat16* __restrict__ xb,
                  const __hip_bfloat16* __restrict__ Wxs0, const __hip_bfloat16* __restrict__ Whs0,
                  const __hip_bfloat16* __restrict__ Wxs1, const __hip_bfloat16* __restrict__ Whs1,
                  const float* __restrict__ bih0, const float* __restrict__ bhh0,
                  const float* __restrict__ bih1, const float* __restrict__ bhh1,
                  __hip_bfloat16* __restrict__ h0seq,   // [HD][BH] circular
                  __hip_bfloat16* __restrict__ h1seq,   // [HD][BH] circular
                  float* __restrict__ out,              // [B][T][H]
                  unsigned* __restrict__ cnt)           // flag/replica lines, 128B stride
{
    const int wg = blockIdx.x, tid = threadIdx.x;
    const int bh = wg >> 7, hg = wg & 127;
    const int wave = tid >> 6, lane = tid & 63;
    const int n = lane & 15, q = lane >> 4;
    const int kh_w = (wave & 3) >> 1;          // K-half within operand
    const int kbb  = (wave & 1) << 3;          // kb base (0 or 8)

    __shared__ float psum[8][16][37];          // [k-slice][batch][tau*16+n]
    __shared__ float res[4][128];              // fp32 h0 hand-off (read at u+2)
    __shared__ __align__(16) unsigned short hstage[2][16][8];
    __shared__ float houtf[16][8];
    __shared__ __align__(16) char ax[32768];       // x[kh][16KB]
    __shared__ __align__(16) char ah0[2][32768];   // h0 dbuf [buf][kh][16KB]
    __shared__ __align__(16) char ah1[32768];      // h1[kh][16KB]

    // ---- load B-fragments once, pin in registers ----
    // sec0 (L0): waves 0-3 -> Wxs0 (x side), waves 4-7 -> Whs0 (h0 side)
    // sec1 (L1): waves 0-3 -> Wxs1 (h0 side), waves 4-7 -> Whs1 (h1 side)
    const __bf16* wb0 = (const __bf16*)(wave < 4 ? Wxs0 : Whs0);
    const __bf16* wb1 = (const __bf16*)(wave < 4 ? Wxs1 : Whs1);

    i32x4_t W0, W1, W2, W3, W4, W5, W6, W7, W8, W9, W10, W11, W12, W13, W14, W15,
            W16, W17, W18, W19, W20, W21, W22, W23, W24, W25, W26, W27, W28, W29, W30, W31;
#define LOADW(IDX, MAT, TAU, J) \
    W##IDX = *(const i32x4_t*)(const void*)((MAT) + \
        ((((((size_t)hg * 2 + (TAU)) * 2 + kh_w) * 16) + (kbb + (J))) * 64 + lane) * 8)
    LOADW(0, wb0, 0, 0);  LOADW(1, wb0, 0, 1);  LOADW(2, wb0, 0, 2);  LOADW(3, wb0, 0, 3);
    LOADW(4, wb0, 0, 4);  LOADW(5, wb0, 0, 5);  LOADW(6, wb0, 0, 6);  LOADW(7, wb0, 0, 7);
    LOADW(8, wb0, 1, 0);  LOADW(9, wb0, 1, 1);  LOADW(10, wb0, 1, 2); LOADW(11, wb0, 1, 3);
    LOADW(12, wb0, 1, 4); LOADW(13, wb0, 1, 5); LOADW(14, wb0, 1, 6); LOADW(15, wb0, 1, 7);
    LOADW(16, wb1, 0, 0); LOADW(17, wb1, 0, 1); LOADW(18, wb1, 0, 2); LOADW(19, wb1, 0, 3);
    LOADW(20, wb1, 0, 4); LOADW(21, wb1, 0, 5); LOADW(22, wb1, 0, 6); LOADW(23, wb1, 0, 7);
    LOADW(24, wb1, 1, 0); LOADW(25, wb1, 1, 1); LOADW(26, wb1, 1, 2); LOADW(27, wb1, 1, 3);
    LOADW(28, wb1, 1, 4); LOADW(29, wb1, 1, 5); LOADW(30, wb1, 1, 6); LOADW(31, wb1, 1, 7);
#undef LOADW
    asm volatile("" : "+v"(W0), "+v"(W1), "+v"(W2), "+v"(W3),
                      "+v"(W4), "+v"(W5), "+v"(W6), "+v"(W7));
    asm volatile("" : "+v"(W8), "+v"(W9), "+v"(W10), "+v"(W11),
                      "+v"(W12), "+v"(W13), "+v"(W14), "+v"(W15));
    asm volatile("" : "+v"(W16), "+v"(W17), "+v"(W18), "+v"(W19),
                      "+v"(W20), "+v"(W21), "+v"(W22), "+v"(W23));
    asm volatile("" : "+v"(W24), "+v"(W25), "+v"(W26), "+v"(W27),
                      "+v"(W28), "+v"(W29), "+v"(W30), "+v"(W31));

    // ---- pointwise thread state: tid<128 = layer 0, tid 128..255 = layer 1 --
    const int pw_L = tid >> 7, pw_idx = tid & 127, pw_b = (tid >> 3) & 15, pw_d = tid & 7;
    float bias_r[4] = {0.f, 0.f, 0.f, 0.f};
    float c_reg = 0.f;
    if (tid < 256) {
        const float* bi  = pw_L ? bih1 : bih0;
        const float* bh2 = pw_L ? bhh1 : bhh0;
#pragma unroll
        for (int g = 0; g < 4; ++g) {
            int row = g * 1024 + hg * 8 + pw_d;
            bias_r[g] = bi[row] + bh2[row];
        }
    }

    const int arow = bh * 16 + n;
    const bool is_master = (hg == bh);
    // cnt lines: flagA[wg]=wg, flagB[wg]=256+wg, replA=512+bh*16+r, replB=544+bh*16+r

    // Kernel-start inv (cross-launch staleness for slots read in phases 0..7)
    if (wave == 0)
        asm volatile("buffer_inv sc0 sc1\n\ts_waitcnt vmcnt(0)" ::: "memory");
    __syncthreads();

    // Prologue: x_0 into ax (waves 2,3; cross-wave visibility via the barrier)
    if (wave == 2 || wave == 3) {
        const int kh2 = wave - 2;
        const __bf16* gx = (const __bf16*)xb + arow * 1024 + kh2 * 512 + q * 8;
        char* ldx = ax + kh2 * 16384;
#pragma unroll
        for (int kb2 = 0; kb2 < 16; ++kb2)
            gload16(gx + kb2 * 32, ldx + kb2 * 1024);
    }
    __syncthreads();   // drains prologue DMA (each wave drains own vmcnt here)

#define MFMA16(AV, WB, ACC) \
    __builtin_amdgcn_mfma_f32_16x16x32_bf16(AV, __builtin_bit_cast(bf16x8_t, WB), ACC, 0, 0, 0)
#define C0STEP(J, IA, IB) { \
    bf16x8_t av = *(const bf16x8_t*)(const void*)(rb0 + (J) * 1024); \
    acc0 = MFMA16(av, W##IA, acc0); acc1 = MFMA16(av, W##IB, acc1); }
#define C1STEP(J, IA, IB) { \
    bf16x8_t av = *(const bf16x8_t*)(const void*)(rb1 + (J) * 1024); \
    acc0 = MFMA16(av, W##IA, acc0); acc1 = MFMA16(av, W##IB, acc1); }

    for (int u = 0; u < NPH; ++u) {
        // ============ relA(u): gate h0 chain (assembled during prev L1) ======
        if (u >= 1) {
            if (is_master) {
                if (tid < 128) {
                    const unsigned* fl = cnt + (size_t)(bh * 128 + tid) * 32;
                    int sp = 0;
                    while (__hip_atomic_load(fl, __ATOMIC_RELAXED,
                                             __HIP_MEMORY_SCOPE_AGENT) < (unsigned)u
                           && sp < 8192) { __builtin_amdgcn_s_sleep(1); ++sp; }
                }
                __syncthreads();
                if (tid < 16)
                    __hip_atomic_store(cnt + (size_t)(512 + bh * 16 + tid) * 32,
                                       (unsigned)u, __ATOMIC_RELAXED, __HIP_MEMORY_SCOPE_AGENT);
            } else {
                if (tid == 0) {
                    const unsigned* rl = cnt + (size_t)(512 + bh * 16 + (hg & 15)) * 32;
                    int sp = 0;
                    while (__hip_atomic_load(rl, __ATOMIC_RELAXED,
                                             __HIP_MEMORY_SCOPE_AGENT) < (unsigned)u
                           && sp < 8192) { __builtin_amdgcn_s_sleep(1); ++sp; }
                }
                __syncthreads();
            }
        }

        // ============ sec0: h0_{u-1} DMA (waves 4-7, self-contained 8KB) =====
        if (wave >= 4 && u <= TT) {
            const __bf16* gsrc = (const __bf16*)h0seq + (size_t)(u & HMASK) * BH
                                 + arow * 1024 + kh_w * 512 + kbb * 32 + q * 8;
            char* ldst = ah0[(u + 1) & 1] + kh_w * 16384 + kbb * 1024;
#pragma unroll
            for (int kb2 = 0; kb2 < 8; ++kb2)
                gload16(gsrc + kb2 * 32, ldst + kb2 * 1024);
            asm volatile("s_waitcnt vmcnt(0)" ::: "memory");
            __builtin_amdgcn_sched_barrier(0);
        }
        // ============ G0: L0 GEMM, all 8 waves (waves 0-3 x-side ready) ======
        if (u < TT) {
            const char* rb0 = (wave < 4 ? ax : ah0[(u + 1) & 1])
                              + kh_w * 16384 + kbb * 1024 + lane * 16;
            f32x4_t acc0 = {0.f, 0.f, 0.f, 0.f};
            f32x4_t acc1 = {0.f, 0.f, 0.f, 0.f};
            C0STEP(0,0,8);  C0STEP(1,1,9);  C0STEP(2,2,10); C0STEP(3,3,11);
            C0STEP(4,4,12); C0STEP(5,5,13); C0STEP(6,6,14); C0STEP(7,7,15);
#pragma unroll
            for (int r = 0; r < 4; ++r) {
                psum[wave][q * 4 + r][n] = acc0[r];
                psum[wave][q * 4 + r][16 + n] = acc1[r];
            }
        }
        __syncthreads();   // sync1: psum ready

        // ============ P0: layer-0 pointwise ================================
        if (tid < 128 && u < TT) {
            float gv[4];
#pragma unroll
            for (int g = 0; g < 4; ++g) {
                const int col = (g >> 1) * 16 + (g & 1) * 8 + pw_d;
                float s = 0.f;
#pragma unroll
                for (int w = 0; w < 8; ++w) s += psum[w][pw_b][col];
                gv[g] = s + bias_r[g];
            }
            float si = 1.f / (1.f + __expf(-gv[0]));
            float sf = 1.f / (1.f + __expf(-gv[1]));
            float tg = 2.f / (1.f + __expf(-2.f * gv[2])) - 1.f;
            float so = 1.f / (1.f + __expf(-gv[3]));
            c_reg = sf * c_reg + si * tg;
            float hv = so * (2.f / (1.f + __expf(-2.f * c_reg)) - 1.f);
            __hip_bfloat16 hb16 = __float2bfloat16(hv);
            unsigned short hraw;
            __builtin_memcpy(&hraw, &hb16, 2);
            hstage[0][pw_b][pw_d] = hraw;
            res[u & 3][pw_idx] = hv;
        }
        __syncthreads();   // sync2: hstage[0]/res ready; psum free for G1

        // ============ S0: h0_u stores + ack + flagA; x-DMA(u+1) =============
        if (wave == 0) {
            if (tid < 16 && u < TT) {
                i32x4_t hv16 = *(const i32x4_t*)(const void*)&hstage[0][tid][0];
                const __hip_bfloat16* dst = h0seq + ((size_t)((u + 1) & HMASK) * BH
                                   + (size_t)(bh * 16 + tid) * 1024 + hg * 8);
                asm volatile("global_store_dwordx4 %0, %1, off sc0 sc1"
                             :: "v"((u64)dst), "v"(hv16) : "memory");
            }
            asm volatile("s_waitcnt vmcnt(0)" ::: "memory");
            if (tid == 0 && u <= TT)
                __hip_atomic_store(cnt + (size_t)wg * 32, (unsigned)(u + 1),
                                   __ATOMIC_RELAXED, __HIP_MEMORY_SCOPE_AGENT);
        } else if ((wave == 2 || wave == 3) && (u + 1 < TT)) {
            const int kh2 = wave - 2;
            const __bf16* gx = (const __bf16*)xb + (size_t)(u + 1) * BH
                               + arow * 1024 + kh2 * 512 + q * 8;
            char* ldx = ax + kh2 * 16384;
#pragma unroll
            for (int kb2 = 0; kb2 < 16; ++kb2)
                gload16(gx + kb2 * 32, ldx + kb2 * 1024);
        }

        // ============ relB(u) + h1 DMA + G1 (sec1, 2<=u<=513) ================
        if (u >= 2) {
            if (is_master) {
                if (tid < 128) {
                    const unsigned* fl = cnt + (size_t)(256 + bh * 128 + tid) * 32;
                    int sp = 0;
                    while (__hip_atomic_load(fl, __ATOMIC_RELAXED,
                                             __HIP_MEMORY_SCOPE_AGENT) < (unsigned)u
                           && sp < 8192) { __builtin_amdgcn_s_sleep(1); ++sp; }
                }
                __syncthreads();
                if (tid < 16)
                    __hip_atomic_store(cnt + (size_t)(544 + bh * 16 + tid) * 32,
                                       (unsigned)u, __ATOMIC_RELAXED, __HIP_MEMORY_SCOPE_AGENT);
            } else {
                if (tid == 0) {
                    const unsigned* rl = cnt + (size_t)(544 + bh * 16 + (hg & 15)) * 32;
                    int sp = 0;
                    while (__hip_atomic_load(rl, __ATOMIC_RELAXED,
                                             __HIP_MEMORY_SCOPE_AGENT) < (unsigned)u
                           && sp < 8192) { __builtin_amdgcn_s_sleep(1); ++sp; }
                }
                __syncthreads();
            }
            // h1_{u-3} DMA (waves 4-7, self-contained); waves 0-3 go straight
            // to their h0-side MFMAs (ah0[u&1] = h0_{u-2}, staged last phase)
            if (wave >= 4) {
                const __bf16* gsrc = (const __bf16*)h1seq + (size_t)((u + 5) & HMASK) * BH
                                     + arow * 1024 + kh_w * 512 + kbb * 32 + q * 8;
                char* ldst = ah1 + kh_w * 16384 + kbb * 1024;
#pragma unroll
                for (int kb2 = 0; kb2 < 8; ++kb2)
                    gload16(gsrc + kb2 * 32, ldst + kb2 * 1024);
                asm volatile("s_waitcnt vmcnt(0)" ::: "memory");
                __builtin_amdgcn_sched_barrier(0);
            }
            const char* rb1 = (wave < 4 ? ah0[u & 1] : ah1)
                              + kh_w * 16384 + kbb * 1024 + lane * 16;
            f32x4_t acc0 = {0.f, 0.f, 0.f, 0.f};
            f32x4_t acc1 = {0.f, 0.f, 0.f, 0.f};
            C1STEP(0,16,24); C1STEP(1,17,25); C1STEP(2,18,26); C1STEP(3,19,27);
            C1STEP(4,20,28); C1STEP(5,21,29); C1STEP(6,22,30); C1STEP(7,23,31);
#pragma unroll
            for (int r = 0; r < 4; ++r) {
                psum[wave][q * 4 + r][n] = acc0[r];
                psum[wave][q * 4 + r][16 + n] = acc1[r];
            }
        }
        __syncthreads();   // sync3: psum ready

        // ============ P1: layer-1 pointwise (timestep u-2) ===================
        if (tid >= 128 && tid < 256 && u >= 2) {
            float gv[4];
#pragma unroll
            for (int g = 0; g < 4; ++g) {
                const int col = (g >> 1) * 16 + (g & 1) * 8 + pw_d;
                float s = 0.f;
#pragma unroll
                for (int w = 0; w < 8; ++w) s += psum[w][pw_b][col];
                gv[g] = s + bias_r[g];
            }
            float si = 1.f / (1.f + __expf(-gv[0]));
            float sf = 1.f / (1.f + __expf(-gv[1]));
            float tg = 2.f / (1.f + __expf(-2.f * gv[2])) - 1.f;
            float so = 1.f / (1.f + __expf(-gv[3]));
            c_reg = sf * c_reg + si * tg;
            float hv = so * (2.f / (1.f + __expf(-2.f * c_reg)) - 1.f);
            __hip_bfloat16 hb16 = __float2bfloat16(hv);
            unsigned short hraw;
            __builtin_memcpy(&hraw, &hb16, 2);
            hstage[1][pw_b][pw_d] = hraw;
            houtf[pw_b][pw_d] = hv;
        }
        __syncthreads();   // sync4: hstage[1]/houtf ready

        // ============ S1: h1_{u-2} stores + ack + flagB; out by wave 1 =======
        if (wave == 0) {
            if (tid < 16 && u >= 2) {
                i32x4_t hv16 = *(const i32x4_t*)(const void*)&hstage[1][tid][0];
                const __hip_bfloat16* dst = h1seq + ((size_t)((u - 2) & HMASK) * BH
                                   + (size_t)(bh * 16 + tid) * 1024 + hg * 8);
                asm volatile("global_store_dwordx4 %0, %1, off sc0 sc1"
                             :: "v"((u64)dst), "v"(hv16) : "memory");
            }
            asm volatile("s_waitcnt vmcnt(0)" ::: "memory");
            if (tid == 0 && u <= TT)
                __hip_atomic_store(cnt + (size_t)(256 + wg) * 32, (unsigned)(u + 1),
                                   __ATOMIC_RELAXED, __HIP_MEMORY_SCOPE_AGENT);
        } else if (wave == 1 && u >= 2) {
            const int j = tid - 64;
            if (j < 32) {
                const int b = j >> 1, hf = j & 1;
                f32x4_t ov;
#pragma unroll
                for (int k = 0; k < 4; ++k)
                    ov[k] = res[(u - 2) & 3][b * 8 + hf * 4 + k] + houtf[b][hf * 4 + k];
                const float* dst = out + (size_t)(bh * 16 + b) * TT * HH
                                       + (size_t)(u - 2) * HH + hg * 8 + hf * 4;
                asm volatile("global_store_dwordx4 %0, %1, off sc0 sc1"
                             :: "v"((u64)dst), "v"(ov) : "memory");
            }
        }

        // ============ inv once per HD phases (slot-cycle boundary) ===========
        if (((u + 1) & HMASK) == 0 && u + 1 < NPH) {
            __syncthreads();
            if (wave == 0)
                asm volatile("buffer_inv sc0 sc1\n\ts_waitcnt vmcnt(0)" ::: "memory");
            __syncthreads();
        }
    }
#undef MFMA16
#undef C0STEP
#undef C1STEP
}

// ---------------------------------------------------------------------------
// Host side
// ---------------------------------------------------------------------------
extern "C" void kernel_launch(void* const* d_in, const int* in_sizes, int n_in,
                              void* d_out, int out_size, void* d_ws, size_t ws_size,
                              hipStream_t stream) {
    const float* x    = (const float*)d_in[0];
    const float* Wih0 = (const float*)d_in[1];
    const float* Whh0 = (const float*)d_in[2];
    const float* bih0 = (const float*)d_in[3];
    const float* bhh0 = (const float*)d_in[4];
    const float* Wih1 = (const float*)d_in[5];
    const float* Whh1 = (const float*)d_in[6];
    const float* bih1 = (const float*)d_in[7];
    const float* bhh1 = (const float*)d_in[8];
    float* out = (float*)d_out;
    (void)in_sizes; (void)n_in; (void)out_size; (void)ws_size;

    // Workspace carve (~65.2 MiB)
    uint8_t* w = (uint8_t*)d_ws;
    const size_t WMAT = (size_t)G4H * HH * 2;   // 8 MiB bf16 per matrix
    __hip_bfloat16* Wxs0 = (__hip_bfloat16*)(w);
    __hip_bfloat16* Whs0 = (__hip_bfloat16*)(w + WMAT);
    __hip_bfloat16* Wxs1 = (__hip_bfloat16*)(w + 2 * WMAT);
    __hip_bfloat16* Whs1 = (__hip_bfloat16*)(w + 3 * WMAT);
    size_t off = 4 * WMAT;
    __hip_bfloat16* xbuf = (__hip_bfloat16*)(w + off); off += (size_t)TT * BB * II * 2;
    __hip_bfloat16* h0seq = (__hip_bfloat16*)(w + off); off += (size_t)HD * BH * 2;
    __hip_bfloat16* h1seq = (__hip_bfloat16*)(w + off); off += (size_t)HD * BH * 2;
    unsigned* cnt = (unsigned*)(w + off); off += 131072;  // 32K words of lines

    init_bufs<<<256, 256, 0, stream>>>((unsigned*)h0seq, (unsigned*)h1seq, cnt);
    shuffle_w<<<(G4H * HH) / 256, 256, 0, stream>>>(Wih0, Wxs0);
    shuffle_w<<<(G4H * HH) / 256, 256, 0, stream>>>(Whh0, Whs0);
    shuffle_w<<<(G4H * HH) / 256, 256, 0, stream>>>(Wih1, Wxs1);
    shuffle_w<<<(G4H * HH) / 256, 256, 0, stream>>>(Whh1, Whs1);
    convert_x<<<(TT * BB * II) / 256, 256, 0, stream>>>(x, xbuf);

    lstm_persist<<<256, 512, 0, stream>>>(xbuf, Wxs0, Whs0, Wxs1, Whs1,
                                          bih0, bhh0, bih1, bhh1,
                                          h0seq, h1seq, out, cnt);
}

// Round 7
// 3132.074 us; speedup vs baseline: 1.1591x; 1.1591x over previous
//
#include <hip/hip_runtime.h>
#include <hip/hip_bf16.h>

// Problem sizes (fixed)
#define BB 32
#define TT 512
#define HH 1024
#define II 1024
#define G4H 4096
#define BH  (BB * HH)          // 32768
#define HD  8                  // h-buffer depth; buffer_inv every HD phases
#define HMASK (HD - 1)
#define NPH (TT + 2)           // 514 phases: L0 @ u (u<512), L1 @ u-2 (u>=2)

typedef __bf16 bf16x8_t __attribute__((ext_vector_type(8)));
typedef float f32x4_t __attribute__((ext_vector_type(4)));
typedef int i32x4_t __attribute__((ext_vector_type(4)));
typedef unsigned long long u64;

// async global(16B/lane) -> LDS(base + lane*16)
__device__ __forceinline__ void gload16(const void* g, void* l) {
    __builtin_amdgcn_global_load_lds(
        (const __attribute__((address_space(1))) unsigned int*)g,
        (__attribute__((address_space(3))) unsigned int*)l, 16, 0, 0);
}

// ---------------------------------------------------------------------------
// Zero h0 slot 0, h1 slot 7 (slots read before first write) + flag lines,
// agent-scope stores (durable at coherence point; ws re-poisoned each call).
// ---------------------------------------------------------------------------
__global__ void init_bufs(unsigned* __restrict__ h0w, unsigned* __restrict__ h1w,
                          unsigned* __restrict__ cnt) {
    int i = blockIdx.x * 256 + threadIdx.x;
    if (i < 16384)
        __hip_atomic_store(h0w + i, 0u, __ATOMIC_RELAXED, __HIP_MEMORY_SCOPE_AGENT);
    else if (i < 32768)
        __hip_atomic_store(h1w + 7 * 16384 + (i - 16384), 0u,
                           __ATOMIC_RELAXED, __HIP_MEMORY_SCOPE_AGENT);
    else if (i < 49152)
        __hip_atomic_store(cnt + (i - 32768), 0u, __ATOMIC_RELAXED, __HIP_MEMORY_SCOPE_AGENT);
    else
        __hip_atomic_store(cnt + 16384 + (i - 49152), 0u,
                           __ATOMIC_RELAXED, __HIP_MEMORY_SCOPE_AGENT);
}

// ---------------------------------------------------------------------------
// Weight shuffle: fp32 [4096][1024] -> bf16 B-fragment order. (unchanged)
// ---------------------------------------------------------------------------
__global__ void shuffle_w(const float* __restrict__ src, __hip_bfloat16* __restrict__ dst) {
    size_t i = (size_t)blockIdx.x * 256 + threadIdx.x;   // 0 .. 4M-1
    int jj   = (int)(i & 7);
    int lane = (int)((i >> 3) & 63);
    int kb   = (int)((i >> 9) & 15);
    int kh   = (int)((i >> 13) & 1);
    int tau  = (int)((i >> 14) & 1);
    int hg   = (int)(i >> 15);
    int n = lane & 15, q = lane >> 4;
    int row = (2 * tau + (n >> 3)) * 1024 + hg * 8 + (n & 7);
    int col = kh * 512 + kb * 32 + q * 8 + jj;
    dst[i] = __float2bfloat16(src[(size_t)row * II + col]);
}

// ---------------------------------------------------------------------------
// x [B][T][I] fp32 -> xb [T][B][I] bf16 (unchanged)
// ---------------------------------------------------------------------------
__global__ void convert_x(const float* __restrict__ x, __hip_bfloat16* __restrict__ xb) {
    size_t i = (size_t)blockIdx.x * 256 + threadIdx.x;   // T*B*I
    int ii = (int)(i & 1023);
    int b  = (int)((i >> 10) & 31);
    int t  = (int)(i >> 15);
    xb[i] = __float2bfloat16(x[((size_t)b * TT + t) * II + ii]);
}

// ---------------------------------------------------------------------------
// Persistent fused 2-layer LSTM — r5 monolithic phase + PER-WAVE gating.
// 256 WGs (1/CU) x 512 threads (8 waves). Wave roles (L=w>>2,p=(w>>1)&1,kh=w&1):
//   w0,1: L0 x-side   — reads ax (self-staged in stage3 of prev phase); NO wait
//   w2,3: L0 h0-side  — reads h0_{u-1}; needs all flags >= u (lag-0, critical)
//   w4,5: L1 h0-side  — reads h0_{u-2}; needs flags >= u-1 (satisfied a phase
//                       ago via the LDS words -> zero wait)
//   w6,7: L1 h1-side  — reads h1_{u-3}; needs flags >= u (own recurrence ring)
// Each LDS A-stream has ONE writer wave == its reader wave -> per-wave
// vmcnt(0)+sched_barrier replaces the old all-wave sync0 entirely.
// Release: direct flag polling (no master, no replicas — r4 showed poller
// density is immaterial): waves 2,3,6,7 each poll 32 of the group's 128 flag
// lines (1 lane/line), then a 4-word LDS handshake ANDs the quarters.
// L1 lags 2 phases (P1 at u computes timestep u-2) so its h0-side input is a
// phase-old certified value. Single sync1/sync2 pair per phase; stores/flag
// as r5 (16B write-through + wave-local vmcnt drain before flag); depth-8
// slots + ONE buffer_inv per 8 phases (staleness proof unchanged; WG skew
// bound <=2 phases << slot ring 8). All spins bounded (hang -> visible fail).
// LDS: 128K streams + 19K psum + 2K res + 1K stage + 16B = ~153 KB.
// ---------------------------------------------------------------------------
__global__ __launch_bounds__(512, 2)
void lstm_persist(const __hip_bfloat16* __restrict__ xb,
                  const __hip_bfloat16* __restrict__ Wxs0, const __hip_bfloat16* __restrict__ Whs0,
                  const __hip_bfloat16* __restrict__ Wxs1, const __hip_bfloat16* __restrict__ Whs1,
                  const float* __restrict__ bih0, const float* __restrict__ bhh0,
                  const float* __restrict__ bih1, const float* __restrict__ bhh1,
                  __hip_bfloat16* __restrict__ h0seq,   // [HD][BH] circular
                  __hip_bfloat16* __restrict__ h1seq,   // [HD][BH] circular
                  float* __restrict__ out,              // [B][T][H]
                  unsigned* __restrict__ cnt)           // flag lines, 128B stride
{
    const int wg = blockIdx.x, tid = threadIdx.x;
    const int bh = wg >> 7, hg = wg & 127;
    const int wave = tid >> 6, lane = tid & 63;
    const int L = wave >> 2, p = (wave >> 1) & 1, kh = wave & 1;
    const int n = lane & 15, q = lane >> 4;

    __shared__ float psum[2][2][2][16][37];   // [L][p][kh][batch][tau*16+n]
    __shared__ float res[4][128];             // fp32 h0 ring (read at u+2)
    __shared__ __align__(16) unsigned short hstage[2][16][8];
    __shared__ float houtf[16][8];
    __shared__ __align__(16) char ax[2][16384];    // x_u      [kh] (w0,w1)
    __shared__ __align__(16) char ah0c[2][16384];  // h0_{u-1} [kh] (w2,w3)
    __shared__ __align__(16) char ah0o[2][16384];  // h0_{u-2} [kh] (w4,w5)
    __shared__ __align__(16) char ah1[2][16384];   // h1_{u-3} [kh] (w6,w7)
    __shared__ unsigned lds_rel[4];           // per-quarter confirmed epoch

    // ---- load B-fragments once, pin in registers (identical to r5) ----
    const __hip_bfloat16* Wsel = L ? (p ? Whs1 : Wxs1) : (p ? Whs0 : Wxs0);
    const __bf16* wbp = (const __bf16*)Wsel;

    i32x4_t W0, W1, W2, W3, W4, W5, W6, W7, W8, W9, W10, W11, W12, W13, W14, W15,
            W16, W17, W18, W19, W20, W21, W22, W23, W24, W25, W26, W27, W28, W29, W30, W31;
#define LOADW(IDX, TAU, KB) \
    W##IDX = *(const i32x4_t*)(const void*)(wbp + ((((((size_t)hg * 2 + (TAU)) * 2 + kh) * 16) + (KB)) * 64 + lane) * 8)
    LOADW(0,0,0);  LOADW(1,0,1);  LOADW(2,0,2);  LOADW(3,0,3);
    LOADW(4,0,4);  LOADW(5,0,5);  LOADW(6,0,6);  LOADW(7,0,7);
    LOADW(8,0,8);  LOADW(9,0,9);  LOADW(10,0,10); LOADW(11,0,11);
    LOADW(12,0,12); LOADW(13,0,13); LOADW(14,0,14); LOADW(15,0,15);
    LOADW(16,1,0);  LOADW(17,1,1);  LOADW(18,1,2);  LOADW(19,1,3);
    LOADW(20,1,4);  LOADW(21,1,5);  LOADW(22,1,6);  LOADW(23,1,7);
    LOADW(24,1,8);  LOADW(25,1,9);  LOADW(26,1,10); LOADW(27,1,11);
    LOADW(28,1,12); LOADW(29,1,13); LOADW(30,1,14); LOADW(31,1,15);
#undef LOADW
    asm volatile("" : "+v"(W0), "+v"(W1), "+v"(W2), "+v"(W3),
                      "+v"(W4), "+v"(W5), "+v"(W6), "+v"(W7));
    asm volatile("" : "+v"(W8), "+v"(W9), "+v"(W10), "+v"(W11),
                      "+v"(W12), "+v"(W13), "+v"(W14), "+v"(W15));
    asm volatile("" : "+v"(W16), "+v"(W17), "+v"(W18), "+v"(W19),
                      "+v"(W20), "+v"(W21), "+v"(W22), "+v"(W23));
    asm volatile("" : "+v"(W24), "+v"(W25), "+v"(W26), "+v"(W27),
                      "+v"(W28), "+v"(W29), "+v"(W30), "+v"(W31));

    // ---- pointwise thread state (as r5: tid<128 = L0, 128..255 = L1) ----
    const int pw_L = tid >> 7, pw_idx = tid & 127, pw_b = (tid >> 3) & 15, pw_d = tid & 7;
    float bias_r[4] = {0.f, 0.f, 0.f, 0.f};
    float c_reg = 0.f;
    if (tid < 256) {
        const float* bi  = pw_L ? bih1 : bih0;
        const float* bh2 = pw_L ? bhh1 : bhh0;
#pragma unroll
        for (int g = 0; g < 4; ++g) {
            int row = g * 1024 + hg * 8 + pw_d;
            bias_r[g] = bi[row] + bh2[row];
        }
    }

    const int arow = bh * 16 + n;
    const bool pollw = (wave == 2 || wave == 3 || wave == 6 || wave == 7);
    const int pidx = (wave == 2) ? 0 : (wave == 3) ? 1 : (wave == 6) ? 2 : 3;

    // Kernel-start inv (cross-launch staleness of h slots read phases 0..7)
    if (wave == 0)
        asm volatile("buffer_inv sc0 sc1\n\ts_waitcnt vmcnt(0)" ::: "memory");
    if (tid < 4) lds_rel[tid] = 0u;
    // Prologue: x_0 self-staged by waves 0,1
    if (wave < 2) {
        const __bf16* gx = (const __bf16*)xb + arow * 1024 + kh * 512 + q * 8;
        char* ldx = ax[kh];
#pragma unroll
        for (int kb2 = 0; kb2 < 16; ++kb2)
            gload16(gx + kb2 * 32, ldx + kb2 * 1024);
    }
    __syncthreads();   // lds_rel init visible (x drained per-wave at phase top)

#define MFMA16(AV, WB, ACC) \
    __builtin_amdgcn_mfma_f32_16x16x32_bf16(AV, __builtin_bit_cast(bf16x8_t, WB), ACC, 0, 0, 0)
#define CSTEP(KB, IA, IB) { \
    bf16x8_t av = *(const bf16x8_t*)(const void*)(rb + (KB) * 1024); \
    acc0 = MFMA16(av, W##IA, acc0); acc1 = MFMA16(av, W##IB, acc1); }

    for (int u = 0; u < NPH; ++u) {
        const bool g0run = (L == 0) && (u < TT);
        const bool g1run = (L == 1) && (u >= 2);

        // ===== per-wave release gate ====================================
        if (pollw) {
            const unsigned tgt = (unsigned)u;
            if (lane < 32) {
                const unsigned* fl = cnt + (size_t)(bh * 128 + pidx * 32 + lane) * 32;
                int sp = 0;
                while (__hip_atomic_load(fl, __ATOMIC_RELAXED,
                                         __HIP_MEMORY_SCOPE_AGENT) < tgt
                       && sp < 8192) { __builtin_amdgcn_s_sleep(1); ++sp; }
            }
            if (lane == 0)
                __hip_atomic_store(&lds_rel[pidx], tgt,
                                   __ATOMIC_RELAXED, __HIP_MEMORY_SCOPE_WORKGROUP);
            int sp = 0;
            for (;;) {
                unsigned m0 = __hip_atomic_load(&lds_rel[0], __ATOMIC_RELAXED, __HIP_MEMORY_SCOPE_WORKGROUP);
                unsigned m1 = __hip_atomic_load(&lds_rel[1], __ATOMIC_RELAXED, __HIP_MEMORY_SCOPE_WORKGROUP);
                unsigned m2 = __hip_atomic_load(&lds_rel[2], __ATOMIC_RELAXED, __HIP_MEMORY_SCOPE_WORKGROUP);
                unsigned m3 = __hip_atomic_load(&lds_rel[3], __ATOMIC_RELAXED, __HIP_MEMORY_SCOPE_WORKGROUP);
                if ((m0 >= tgt && m1 >= tgt && m2 >= tgt && m3 >= tgt) || sp >= 16384) break;
                __builtin_amdgcn_s_sleep(1); ++sp;
            }
        } else if ((wave == 4 || wave == 5) && g1run) {
            const unsigned tgt = (unsigned)(u - 1);   // satisfied a phase ago
            int sp = 0;
            for (;;) {
                unsigned m0 = __hip_atomic_load(&lds_rel[0], __ATOMIC_RELAXED, __HIP_MEMORY_SCOPE_WORKGROUP);
                unsigned m1 = __hip_atomic_load(&lds_rel[1], __ATOMIC_RELAXED, __HIP_MEMORY_SCOPE_WORKGROUP);
                unsigned m2 = __hip_atomic_load(&lds_rel[2], __ATOMIC_RELAXED, __HIP_MEMORY_SCOPE_WORKGROUP);
                unsigned m3 = __hip_atomic_load(&lds_rel[3], __ATOMIC_RELAXED, __HIP_MEMORY_SCOPE_WORKGROUP);
                if ((m0 >= tgt && m1 >= tgt && m2 >= tgt && m3 >= tgt) || sp >= 16384) break;
                __builtin_amdgcn_s_sleep(1); ++sp;
            }
        }

        // ===== per-wave DMA + drain (stream writer == stream reader) =====
        if (g0run && p == 1) {            // w2,3: h0_{u-1} -> slot u&7
            const __bf16* gsrc = (const __bf16*)h0seq + (size_t)(u & HMASK) * BH
                                 + arow * 1024 + kh * 512 + q * 8;
            char* ldst = ah0c[kh];
#pragma unroll
            for (int kb2 = 0; kb2 < 16; ++kb2)
                gload16(gsrc + kb2 * 32, ldst + kb2 * 1024);
            asm volatile("s_waitcnt vmcnt(0)" ::: "memory");
            __builtin_amdgcn_sched_barrier(0);
        } else if (g1run && p == 0) {     // w4,5: h0_{u-2} -> slot (u-1)&7
            const __bf16* gsrc = (const __bf16*)h0seq + (size_t)((u + 7) & HMASK) * BH
                                 + arow * 1024 + kh * 512 + q * 8;
            char* ldst = ah0o[kh];
#pragma unroll
            for (int kb2 = 0; kb2 < 16; ++kb2)
                gload16(gsrc + kb2 * 32, ldst + kb2 * 1024);
            asm volatile("s_waitcnt vmcnt(0)" ::: "memory");
            __builtin_amdgcn_sched_barrier(0);
        } else if (g1run && p == 1) {     // w6,7: h1_{u-3} -> slot (u+5)&7
            const __bf16* gsrc = (const __bf16*)h1seq + (size_t)((u + 5) & HMASK) * BH
                                 + arow * 1024 + kh * 512 + q * 8;
            char* ldst = ah1[kh];
#pragma unroll
            for (int kb2 = 0; kb2 < 16; ++kb2)
                gload16(gsrc + kb2 * 32, ldst + kb2 * 1024);
            asm volatile("s_waitcnt vmcnt(0)" ::: "memory");
            __builtin_amdgcn_sched_barrier(0);
        } else if (g0run && p == 0) {     // w0,1: drain own x-DMA (prev stage3)
            asm volatile("s_waitcnt vmcnt(0)" ::: "memory");
            __builtin_amdgcn_sched_barrier(0);
        }

        // ===== GEMM =====================================================
        if (g0run || g1run) {
            const char* rb = (L == 0 ? (p == 0 ? ax[kh] : ah0c[kh])
                                     : (p == 0 ? ah0o[kh] : ah1[kh])) + lane * 16;
            f32x4_t acc0 = {0.f, 0.f, 0.f, 0.f};
            f32x4_t acc1 = {0.f, 0.f, 0.f, 0.f};
            CSTEP(0,0,16);  CSTEP(1,1,17);  CSTEP(2,2,18);  CSTEP(3,3,19);
            CSTEP(4,4,20);  CSTEP(5,5,21);  CSTEP(6,6,22);  CSTEP(7,7,23);
            CSTEP(8,8,24);  CSTEP(9,9,25);  CSTEP(10,10,26); CSTEP(11,11,27);
            CSTEP(12,12,28); CSTEP(13,13,29); CSTEP(14,14,30); CSTEP(15,15,31);
#pragma unroll
            for (int r = 0; r < 4; ++r) {
                psum[L][p][kh][q * 4 + r][n] = acc0[r];
                psum[L][p][kh][q * 4 + r][16 + n] = acc1[r];
            }
        }
        __syncthreads();   // sync1: psum ready

        // ===== pointwise: P0 = timestep u (u<512); P1 = timestep u-2 =====
        if (tid < 256) {
            const bool active = pw_L ? (u >= 2) : (u < TT);
            if (active) {
                float gv[4];
#pragma unroll
                for (int g = 0; g < 4; ++g) {
                    int col = (g >> 1) * 16 + (g & 1) * 8 + pw_d;
                    gv[g] = psum[pw_L][0][0][pw_b][col] + psum[pw_L][0][1][pw_b][col]
                          + psum[pw_L][1][0][pw_b][col] + psum[pw_L][1][1][pw_b][col]
                          + bias_r[g];
                }
                float si = 1.f / (1.f + __expf(-gv[0]));
                float sf = 1.f / (1.f + __expf(-gv[1]));
                float tg = 2.f / (1.f + __expf(-2.f * gv[2])) - 1.f;
                float so = 1.f / (1.f + __expf(-gv[3]));
                c_reg = sf * c_reg + si * tg;
                float hv = so * (2.f / (1.f + __expf(-2.f * c_reg)) - 1.f);
                __hip_bfloat16 hb16 = __float2bfloat16(hv);
                unsigned short hraw;
                __builtin_memcpy(&hraw, &hb16, 2);
                hstage[pw_L][pw_b][pw_d] = hraw;
                if (pw_L == 0) res[u & 3][pw_idx] = hv;
                else           houtf[pw_b][pw_d] = hv;
            }
        }
        __syncthreads();   // sync2: hstage/houtf/res ready

        // ===== stage3: w0 = h stores+ack+flag+x; w1 = out+x ==============
        if (wave == 0) {
            if (tid < 32) {
                const int gl = tid >> 4, b = tid & 15;
                const bool go = gl ? (u >= 2) : (u < TT);
                if (go) {
                    i32x4_t hv16 = *(const i32x4_t*)(const void*)&hstage[gl][b][0];
                    const __hip_bfloat16* dst = gl
                        ? h1seq + ((size_t)((u - 2) & HMASK) * BH
                                   + (size_t)(bh * 16 + b) * 1024 + hg * 8)
                        : h0seq + ((size_t)((u + 1) & HMASK) * BH
                                   + (size_t)(bh * 16 + b) * 1024 + hg * 8);
                    asm volatile("global_store_dwordx4 %0, %1, off sc0 sc1"
                                 :: "v"((u64)dst), "v"(hv16) : "memory");
                }
            }
            asm volatile("s_waitcnt vmcnt(0)" ::: "memory");   // ack at IF
            if (tid == 0 && u <= TT)
                __hip_atomic_store(cnt + (size_t)wg * 32, (unsigned)(u + 1),
                                   __ATOMIC_RELAXED, __HIP_MEMORY_SCOPE_AGENT);
            if (u + 1 < TT) {          // x_{u+1} kh0, after the flag
                const __bf16* gx = (const __bf16*)xb + (size_t)(u + 1) * BH
                                   + arow * 1024 + q * 8;
#pragma unroll
                for (int kb2 = 0; kb2 < 16; ++kb2)
                    gload16(gx + kb2 * 32, ax[0] + kb2 * 1024);
            }
        } else if (wave == 1) {
            if (u >= 2) {
                const int j = tid - 64;
                if (j < 32) {
                    const int b = j >> 1, hf = j & 1;
                    f32x4_t ov;
#pragma unroll
                    for (int k = 0; k < 4; ++k)
                        ov[k] = res[(u - 2) & 3][b * 8 + hf * 4 + k] + houtf[b][hf * 4 + k];
                    const float* dst = out + (size_t)(bh * 16 + b) * TT * HH
                                           + (size_t)(u - 2) * HH + hg * 8 + hf * 4;
                    asm volatile("global_store_dwordx4 %0, %1, off sc0 sc1"
                                 :: "v"((u64)dst), "v"(ov) : "memory");
                }
            }
            if (u + 1 < TT) {          // x_{u+1} kh1
                const __bf16* gx = (const __bf16*)xb + (size_t)(u + 1) * BH
                                   + arow * 1024 + 512 + q * 8;
#pragma unroll
                for (int kb2 = 0; kb2 < 16; ++kb2)
                    gload16(gx + kb2 * 32, ax[1] + kb2 * 1024);
            }
        }

        // ===== inv once per HD phases (uniform across waves) =============
        if (((u + 1) & HMASK) == 0 && (u + 1) < NPH) {
            __syncthreads();
            if (wave == 0)
                asm volatile("buffer_inv sc0 sc1\n\ts_waitcnt vmcnt(0)" ::: "memory");
            __syncthreads();
        }
    }
#undef MFMA16
#undef CSTEP
}

// ---------------------------------------------------------------------------
// Host side
// ---------------------------------------------------------------------------
extern "C" void kernel_launch(void* const* d_in, const int* in_sizes, int n_in,
                              void* d_out, int out_size, void* d_ws, size_t ws_size,
                              hipStream_t stream) {
    const float* x    = (const float*)d_in[0];
    const float* Wih0 = (const float*)d_in[1];
    const float* Whh0 = (const float*)d_in[2];
    const float* bih0 = (const float*)d_in[3];
    const float* bhh0 = (const float*)d_in[4];
    const float* Wih1 = (const float*)d_in[5];
    const float* Whh1 = (const float*)d_in[6];
    const float* bih1 = (const float*)d_in[7];
    const float* bhh1 = (const float*)d_in[8];
    float* out = (float*)d_out;
    (void)in_sizes; (void)n_in; (void)out_size; (void)ws_size;

    // Workspace carve (~65.2 MiB)
    uint8_t* w = (uint8_t*)d_ws;
    const size_t WMAT = (size_t)G4H * HH * 2;   // 8 MiB bf16 per matrix
    __hip_bfloat16* Wxs0 = (__hip_bfloat16*)(w);
    __hip_bfloat16* Whs0 = (__hip_bfloat16*)(w + WMAT);
    __hip_bfloat16* Wxs1 = (__hip_bfloat16*)(w + 2 * WMAT);
    __hip_bfloat16* Whs1 = (__hip_bfloat16*)(w + 3 * WMAT);
    size_t off = 4 * WMAT;
    __hip_bfloat16* xbuf = (__hip_bfloat16*)(w + off); off += (size_t)TT * BB * II * 2;
    __hip_bfloat16* h0seq = (__hip_bfloat16*)(w + off); off += (size_t)HD * BH * 2;
    __hip_bfloat16* h1seq = (__hip_bfloat16*)(w + off); off += (size_t)HD * BH * 2;
    unsigned* cnt = (unsigned*)(w + off); off += 131072;  // 32K words of lines

    init_bufs<<<256, 256, 0, stream>>>((unsigned*)h0seq, (unsigned*)h1seq, cnt);
    shuffle_w<<<(G4H * HH) / 256, 256, 0, stream>>>(Wih0, Wxs0);
    shuffle_w<<<(G4H * HH) / 256, 256, 0, stream>>>(Whh0, Whs0);
    shuffle_w<<<(G4H * HH) / 256, 256, 0, stream>>>(Wih1, Wxs1);
    shuffle_w<<<(G4H * HH) / 256, 256, 0, stream>>>(Whh1, Whs1);
    convert_x<<<(TT * BB * II) / 256, 256, 0, stream>>>(x, xbuf);

    lstm_persist<<<256, 512, 0, stream>>>(xbuf, Wxs0, Whs0, Wxs1, Whs1,
                                          bih0, bhh0, bih1, bhh1,
                                          h0seq, h1seq, out, cnt);
}